// Round 4
// baseline (510.834 us; speedup 1.0000x reference)
//
#include <hip/hip_runtime.h>
#include <hip/hip_bf16.h>
#include <math.h>

// All inputs are FLOAT32 (per setup_inputs: jnp.float32). Output is FLOAT32
// (the reference returns fp32).

// ---------------------------------------------------------------------------
// Kernel 1: KNN exactly replicating the np/fp32 reference:
//   sq[i]  = ((x*x + y*y) + z*z)                 (fp32, no FMA)
//   dot    = ((xi*xj + yi*yj) + zi*zj)           (fp32, no FMA)
//   d[i][j]= (sq[i] + sq[j]) - 2*dot             (fp32, each step rounded)
//   top_k(-d, 101) stable (ties -> lower index), drop rank 0.
// One wave per row, 4 rows per 256-thread block.
// Outputs: idx_out[row][100] = GLOBAL neighbor row index (sorted by distance),
// nd_out[row][100][3] = normalized direction (fp32).
// ---------------------------------------------------------------------------
__global__ __launch_bounds__(256) void knn_kernel(const float* __restrict__ verts,
                                                  int* __restrict__ idx_out,
                                                  float* __restrict__ nd_out)
{
    __shared__ float vx[1024], vy[1024], vz[1024];
    __shared__ float sq[1024];
    const int tid = threadIdx.x;
    const int row0 = blockIdx.x * 4;
    const int b = row0 >> 10;            // 1024 % 4 == 0 -> block never crosses batch
    const float* vb = verts + b * 3072;

    for (int t = tid; t < 3072; t += 256) {
        float v = vb[t];
        int n = t / 3, c = t - n * 3;
        if (c == 0) vx[n] = v; else if (c == 1) vy[n] = v; else vz[n] = v;
    }
    __syncthreads();
    for (int n = tid; n < 1024; n += 256) {
        float x = vx[n], y = vy[n], z = vz[n];
        sq[n] = __fadd_rn(__fadd_rn(__fmul_rn(x, x), __fmul_rn(y, y)),
                          __fmul_rn(z, z));
    }
    __syncthreads();

    const int w = tid >> 6, lane = tid & 63;
    const int row = row0 + w;            // global row in [0,4096)
    const int n_i = row & 1023;
    const float xi = vx[n_i], yi = vy[n_i], zi = vz[n_i];
    const float sqi = sq[n_i];

    float dloc[16];
    unsigned taken = 0u;                 // self IS a candidate (ref drops rank 0)
#pragma unroll
    for (int t = 0; t < 16; ++t) {
        int j = t * 64 + lane;
        float dot = __fadd_rn(__fadd_rn(__fmul_rn(xi, vx[j]),
                                        __fmul_rn(yi, vy[j])),
                              __fmul_rn(zi, vz[j]));
        dloc[t] = __fsub_rn(__fadd_rn(sqi, sq[j]), __fmul_rn(2.0f, dot));
    }

    const int rowbase = row & ~1023;     // batch base for global indices
    for (int it = 0; it < 101; ++it) {
        float bd = 3.4e38f; int bj = 0x7fffffff;
#pragma unroll
        for (int t = 0; t < 16; ++t) {
            bool ok = ((taken >> t) & 1u) == 0u;
            if (ok && dloc[t] < bd) { bd = dloc[t]; bj = t * 64 + lane; }
        }
#pragma unroll
        for (int off = 1; off < 64; off <<= 1) {
            float od = __shfl_xor(bd, off);
            int   oj = __shfl_xor(bj, off);
            if (od < bd || (od == bd && oj < bj)) { bd = od; bj = oj; }
        }
        // all lanes now hold the global (bd, bj); owner lane marks it taken
        if ((bj & 63) == lane) {
            int tsel = bj >> 6;
#pragma unroll
            for (int t = 0; t < 16; ++t) if (t == tsel) taken |= (1u << t);
        }
        if (it > 0 && lane == 0) {
            int slot = it - 1;
            idx_out[row * 100 + slot] = rowbase + bj;
            float dx = vx[bj] - xi, dy = vy[bj] - yi, dz = vz[bj] - zi;
            float nrm = sqrtf(__fadd_rn(__fadd_rn(__fmul_rn(dx, dx),
                                                  __fmul_rn(dy, dy)),
                                        __fmul_rn(dz, dz)));
            float inv = 1.0f / fmaxf(nrm, 1e-12f);
            float* o = nd_out + (row * 100 + slot) * 3;
            o[0] = dx * inv; o[1] = dy * inv; o[2] = dz * inv;
        }
    }
}

// ---------------------------------------------------------------------------
// Kernel 2: fused surface conv for all 3 scales (k=5/20/100 are prefixes of
// the sorted neighbor list). Block = 128 threads = one row; thread d owns
// output channel d. raw = max_k relu(nd_k . ndir_d).
// ---------------------------------------------------------------------------
__global__ __launch_bounds__(128) void surf3_kernel(const float* __restrict__ nd,
    const float* __restrict__ dl, const float* __restrict__ dm, const float* __restrict__ dg,
    float* __restrict__ raw_l, float* __restrict__ raw_m, float* __restrict__ raw_g)
{
    __shared__ float nds[300];
    const int d = threadIdx.x;
    const int row = blockIdx.x;

    float lx = dl[d], ly = dl[128 + d], lz = dl[256 + d];
    float li = 1.0f / fmaxf(sqrtf((lx * lx + ly * ly) + lz * lz), 1e-12f);
    lx *= li; ly *= li; lz *= li;
    float mx = dm[d], my = dm[128 + d], mz = dm[256 + d];
    float mi = 1.0f / fmaxf(sqrtf((mx * mx + my * my) + mz * mz), 1e-12f);
    mx *= mi; my *= mi; mz *= mi;
    float gx = dg[d], gy = dg[128 + d], gz = dg[256 + d];
    float gi = 1.0f / fmaxf(sqrtf((gx * gx + gy * gy) + gz * gz), 1e-12f);
    gx *= gi; gy *= gi; gz *= gi;

    for (int t = d; t < 300; t += 128) nds[t] = nd[row * 300 + t];
    __syncthreads();

    float ml = -1e30f, mm = -1e30f, mg = -1e30f;
    for (int k = 0; k < 100; ++k) {
        float x = nds[3 * k], y = nds[3 * k + 1], z = nds[3 * k + 2];
        float tg = (x * gx + y * gy) + z * gz;
        mg = fmaxf(mg, tg);
        if (k < 20) { float tm = (x * mx + y * my) + z * mz; mm = fmaxf(mm, tm); }
        if (k < 5)  { float tl = (x * lx + y * ly) + z * lz; ml = fmaxf(ml, tl); }
    }
    raw_l[row * 128 + d] = fmaxf(ml, 0.0f);   // max of relu == relu of max (k>=1)
    raw_m[row * 128 + d] = fmaxf(mm, 0.0f);
    raw_g[row * 128 + d] = fmaxf(mg, 0.0f);
}

// ---------------------------------------------------------------------------
// Kernel 3: batchnorm stats (fp64) -> per-channel affine (a, b2) so that
// bn_relu(x) = relu(a*x + b2).  Grid = nt*128 blocks (1 wave each).
// st[c] = a, st[128+c] = b2.
// ---------------------------------------------------------------------------
__global__ __launch_bounds__(64) void stats_kernel(
    const float* s0, const float* s1, const float* s2,
    const float* g0, const float* g1, const float* g2,
    const float* e0, const float* e1, const float* e2,
    float* o0, float* o1, float* o2)
{
    const int t = blockIdx.x >> 7;
    const int c = blockIdx.x & 127;
    const float* src = (t == 0) ? s0 : (t == 1) ? s1 : s2;
    const float* g = (t == 0) ? g0 : (t == 1) ? g1 : g2;
    const float* e = (t == 0) ? e0 : (t == 1) ? e1 : e2;
    float* o = (t == 0) ? o0 : (t == 1) ? o1 : o2;
    const int lane = threadIdx.x;
    double s = 0.0, q = 0.0;
    for (int r = lane; r < 4096; r += 64) {
        double v = (double)src[r * 128 + c];
        s += v; q += v * v;
    }
#pragma unroll
    for (int off = 32; off; off >>= 1) {
        s += __shfl_down(s, off);
        q += __shfl_down(q, off);
    }
    if (lane == 0) {
        double m = s * (1.0 / 4096.0);
        double var = q * (1.0 / 4096.0) - m * m;
        double a = (double)g[c] / sqrt(var + 1e-5);
        o[c] = (float)a;
        o[128 + c] = (float)((double)e[c] - m * a);
    }
}

// ---------------------------------------------------------------------------
// Kernel 4: GEMM out[r][o] = bias[o] + sum_c relu(a_c*x_c + b_c) * W[c][o]
// A assembled from up to 3 source tensors (128 channels each). Output fp32;
// final_relu applies relu. Block 256 threads = 256 output cols x 16 rows.
// ---------------------------------------------------------------------------
__global__ __launch_bounds__(256) void gemm_kernel(
    const float* __restrict__ A0, const float* __restrict__ A1, const float* __restrict__ A2,
    const float* __restrict__ st0, const float* __restrict__ st1, const float* __restrict__ st2,
    const float* __restrict__ W, const float* __restrict__ bias,
    float* __restrict__ out, int nseg, int final_relu)
{
    __shared__ float As[16 * 384];
    const int o = threadIdx.x;
    const int r0 = blockIdx.x * 16;
    const int CIN = nseg * 128;

    for (int t = o; t < 16 * CIN; t += 256) {
        int r = t / CIN, c = t - r * CIN;
        int seg = c >> 7, cc = c & 127;
        const float* A = (seg == 0) ? A0 : (seg == 1) ? A1 : A2;
        const float* st = (seg == 0) ? st0 : (seg == 1) ? st1 : st2;
        float v = A[(r0 + r) * 128 + cc];
        As[t] = fmaxf(fmaf(st[cc], v, st[128 + cc]), 0.0f);
    }
    __syncthreads();

    float acc[16];
    const float bz = bias[o];
#pragma unroll
    for (int r = 0; r < 16; ++r) acc[r] = bz;

    for (int c = 0; c < CIN; c += 4) {
        float w0 = W[(c + 0) * 256 + o];
        float w1 = W[(c + 1) * 256 + o];
        float w2 = W[(c + 2) * 256 + o];
        float w3 = W[(c + 3) * 256 + o];
#pragma unroll
        for (int r = 0; r < 16; ++r) {
            const float4 av = *(const float4*)&As[r * CIN + c];
            acc[r] += av.x * w0 + av.y * w1 + av.z * w2 + av.w * w3;
        }
    }
    if (final_relu) {
#pragma unroll
        for (int r = 0; r < 16; ++r)
            out[(r0 + r) * 256 + o] = fmaxf(acc[r], 0.0f);
    } else {
#pragma unroll
        for (int r = 0; r < 16; ++r)
            out[(r0 + r) * 256 + o] = acc[r];
    }
}

// ---------------------------------------------------------------------------
// Kernel 5: conv-layer apply: out[r][d] = fo[r][d] + max_k relu(nd_k.ndir_d)*fo[idx_k][128+d]
// Up to 2 jobs via blockIdx.y (different dirs / fo / K).
// ---------------------------------------------------------------------------
__global__ __launch_bounds__(128) void layer_kernel(
    const float* __restrict__ nd, const int* __restrict__ idxbuf,
    const float* dir0, const float* fo0, float* out0, int K0,
    const float* dir1, const float* fo1, float* out1, int K1)
{
    const int job = blockIdx.y;
    const float* dirs = job ? dir1 : dir0;
    const float* fo = job ? fo1 : fo0;
    float* out = job ? out1 : out0;
    const int K = job ? K1 : K0;

    __shared__ float nds[300];
    __shared__ int idxs[100];
    const int d = threadIdx.x;
    const int row = blockIdx.x;

    float dx = dirs[d], dy = dirs[128 + d], dz = dirs[256 + d];
    float di = 1.0f / fmaxf(sqrtf((dx * dx + dy * dy) + dz * dz), 1e-12f);
    dx *= di; dy *= di; dz *= di;

    for (int t = d; t < K * 3; t += 128) nds[t] = nd[row * 300 + t];
    for (int t = d; t < K; t += 128) idxs[t] = idxbuf[row * 100 + t];
    __syncthreads();

    float acc = -1e30f;
    for (int k = 0; k < K; ++k) {
        float x = nds[3 * k], y = nds[3 * k + 1], z = nds[3 * k + 2];
        float th = fmaxf((x * dx + y * dy) + z * dz, 0.0f);
        float fs = fo[idxs[k] * 256 + 128 + d];   // idx is a GLOBAL row index
        acc = fmaxf(acc, th * fs);
    }
    out[row * 128 + d] = fo[row * 256 + d] + acc;
}

// ---------------------------------------------------------------------------
extern "C" void kernel_launch(void* const* d_in, const int* in_sizes, int n_in,
                              void* d_out, int out_size, void* d_ws, size_t ws_size,
                              hipStream_t stream)
{
    (void)in_sizes; (void)n_in; (void)out_size; (void)ws_size;

    const float* verts   = (const float*)d_in[0];
    const float* dirs_l  = (const float*)d_in[1];
    const float* dirs_m0 = (const float*)d_in[2];
    const float* W_m1    = (const float*)d_in[3];
    const float* b_m1    = (const float*)d_in[4];
    const float* dirs_m1 = (const float*)d_in[5];
    const float* dirs_g0 = (const float*)d_in[6];
    const float* W_g1    = (const float*)d_in[7];
    const float* b_g1    = (const float*)d_in[8];
    const float* dirs_g1 = (const float*)d_in[9];
    const float* W_g2    = (const float*)d_in[10];
    const float* b_g2    = (const float*)d_in[11];
    const float* dirs_g2 = (const float*)d_in[12];
    const float* g_l  = (const float*)d_in[13]; const float* be_l  = (const float*)d_in[14];
    const float* g_m0 = (const float*)d_in[15]; const float* be_m0 = (const float*)d_in[16];
    const float* g_m1 = (const float*)d_in[17]; const float* be_m1 = (const float*)d_in[18];
    const float* g_g0 = (const float*)d_in[19]; const float* be_g0 = (const float*)d_in[20];
    const float* g_g1 = (const float*)d_in[21]; const float* be_g1 = (const float*)d_in[22];
    const float* g_g2 = (const float*)d_in[23]; const float* be_g2 = (const float*)d_in[24];
    const float* W_down = (const float*)d_in[25];
    const float* b_down = (const float*)d_in[26];

    char* ws = (char*)d_ws;
    int*   idx100 = (int*)  (ws + 0);                       // 1.6384 MB
    float* st_l   = (float*)(ws + 0x1A0000);                // 6 stat blocks of 1 KB
    float* st_m0  = st_l + 256;
    float* st_m1  = st_l + 512;
    float* st_g0  = st_l + 768;
    float* st_g1  = st_l + 1024;
    float* st_g2  = st_l + 1280;
    float* nd100  = (float*)(ws + (size_t)( 2 << 20));      // 4.9152 MB
    float* raw_l  = (float*)(ws + (size_t)( 8 << 20));      // 2 MB each
    float* raw_m0 = (float*)(ws + (size_t)(10 << 20));
    float* raw_g0 = (float*)(ws + (size_t)(12 << 20));
    float* raw_m1 = (float*)(ws + (size_t)(14 << 20));
    float* raw_g1 = (float*)(ws + (size_t)(16 << 20));
    float* raw_g2 = (float*)(ws + (size_t)(18 << 20));
    float* fo_m   = (float*)(ws + (size_t)(20 << 20));      // 4 MB each
    float* fo_g   = (float*)(ws + (size_t)(24 << 20));
    float* fo_g2  = (float*)(ws + (size_t)(28 << 20));

    // 1. KNN + neighbor directions
    knn_kernel<<<1024, 256, 0, stream>>>(verts, idx100, nd100);
    // 2. surface convs (l: k=5, m0: k=20, g0: k=100)
    surf3_kernel<<<4096, 128, 0, stream>>>(nd100, dirs_l, dirs_m0, dirs_g0,
                                           raw_l, raw_m0, raw_g0);
    // 3. bn stats for l, m0, g0
    stats_kernel<<<384, 64, 0, stream>>>(raw_l, raw_m0, raw_g0,
                                         g_l, g_m0, g_g0, be_l, be_m0, be_g0,
                                         st_l, st_m0, st_g0);
    // 4/5. fo = bn_relu(raw) @ W + bias
    gemm_kernel<<<256, 256, 0, stream>>>(raw_m0, nullptr, nullptr,
                                         st_m0, nullptr, nullptr,
                                         W_m1, b_m1, fo_m, 1, 0);
    gemm_kernel<<<256, 256, 0, stream>>>(raw_g0, nullptr, nullptr,
                                         st_g0, nullptr, nullptr,
                                         W_g1, b_g1, fo_g, 1, 0);
    // 6. conv-layer apply (m1: K=20, g1: K=100)
    layer_kernel<<<dim3(4096, 2), 128, 0, stream>>>(nd100, idx100,
                                                    dirs_m1, fo_m, raw_m1, 20,
                                                    dirs_g1, fo_g, raw_g1, 100);
    // 7. bn stats for m1, g1
    stats_kernel<<<256, 64, 0, stream>>>(raw_m1, raw_g1, raw_g1,
                                         g_m1, g_g1, g_g1, be_m1, be_g1, be_g1,
                                         st_m1, st_g1, st_g1);
    // 8. fo_g2
    gemm_kernel<<<256, 256, 0, stream>>>(raw_g1, nullptr, nullptr,
                                         st_g1, nullptr, nullptr,
                                         W_g2, b_g2, fo_g2, 1, 0);
    // 9. conv-layer apply (g2: K=100)
    layer_kernel<<<dim3(4096, 1), 128, 0, stream>>>(nd100, idx100,
                                                    dirs_g2, fo_g2, raw_g2, 100,
                                                    dirs_g2, fo_g2, raw_g2, 100);
    // 10. bn stats for g2
    stats_kernel<<<128, 64, 0, stream>>>(raw_g2, raw_g2, raw_g2,
                                         g_g2, g_g2, g_g2, be_g2, be_g2, be_g2,
                                         st_g2, st_g2, st_g2);
    // 11. final: relu(concat(bn_relu each) @ W_down + b_down) -> FP32 output
    gemm_kernel<<<256, 256, 0, stream>>>(raw_l, raw_m1, raw_g2,
                                         st_l, st_m1, st_g2,
                                         W_down, b_down, (float*)d_out, 3, 1);
}